// Round 9
// baseline (99.194 us; speedup 1.0000x reference)
//
#include <hip/hip_runtime.h>
#include <math.h>

// CapsuleLayer dynamic routing, factored (u_hat never materialized):
//   s[b,m,:] = ((Sum_n e_n in[b,n,:]) / Sum_n e_n) @ W[:,m,:],  e_n = exp(logit)
//   logit linear in per-pass wv updates -> CUMULATIVE wv (in registers),
//   no per-n state. Pass 0 (uniform softmax) = plain column sum.
//
// R8 lesson: halving L1 touches + packing VALU was NEUTRAL at halved TLP ->
// the wall is per-wave latency + barrier/tail serialization (9 barriers, and
// 15/16 waves idle during each single-wave tail). R9:
//  (1) REDUNDANT tail: every wave sums red[] itself, computes squash + wv in
//      registers (lane=(m,d)); redistribution to g-loop layout via bpermute.
//      No cum/fin LDS, no serial tail.
//  (2) 2 barriers/pass (5 total) instead of 3 (9 total).
//  (3) TPB=1024, grid 512 = 64 b x 8 m-quads -> 2 blocks/CU x 16 waves =
//      32 waves/CU AND only 2 input re-reads/CU/pass (R7+R8 combined).
// Proven pieces kept: dense reads (lane=(row,c4), 1 instr = 64 distinct
// lines), quad dot via DPP quad_perm, 16-lane harvest via row_shl:4/8 (sums
// land in lanes 0..3) + symmetric xor16/32, pk_fma float2 math, W in LDS
// stride 65 (2-way alias = free), b = bx&63 pins batch to XCD b%8,
// launch_bounds(.,4) -> 64-VGPR budget (compiler rule 256/min_waves, R1-R5).

#define TPB 1024

typedef float vf2 __attribute__((ext_vector_type(2)));

// x + dpp_shuffled(x); bound_ctrl=true -> out-of-pattern lanes contribute 0
#define DPP_ADDF(x, ctrl) \
    ((x) + __int_as_float(__builtin_amdgcn_update_dpp( \
        0, __float_as_int(x), (ctrl), 0xF, 0xF, true)))
// quad_perm xor1 = 0xB1, xor2 = 0x4E; row_shl:4 = 0x104, row_shl:8 = 0x108

__global__ __launch_bounds__(TPB, 4)
void capsule_routing_kernel(const float* __restrict__ in,
                            const float* __restrict__ W,
                            float* __restrict__ out)
{
    __shared__ float red[16 * 68];   // [wave][m*17 + {S, xc[16]}]
    __shared__ float w_lds[16 * 65]; // W[d][mi*16+c], stride 65

    const int tid = threadIdx.x;
    const int w   = tid >> 6;        // 0..15
    const int l   = tid & 63;
    const int c4  = l & 3;           // g-loop: dims 4*c4..4*c4+3 of row
    const int tmi = l >> 4;          // tail: m within quad (0..3)
    const int tc  = l & 15;          // tail: c / d index
    const int b   = blockIdx.x & 63;
    const int m0  = (blockIdx.x >> 6) << 2;

    // dense: lane l reads float4 #(w*512 + g*64 + l); wave w owns rows
    // w*128..w*128+127 (g = 0..7)
    const float4* __restrict__ inb4 =
        (const float4*)(in + ((size_t)b << 15)) + ((w << 9) + l);

    // stage W[:, m0:m0+4, :] (1024 floats) -> LDS, one element per thread.
    // (pass-0's post-reduce __syncthreads orders these writes before any read)
    w_lds[(tid >> 6) * 65 + (tid & 63)] = W[((tid >> 6) << 9) + (m0 << 4) + (tid & 63)];

    vf2 wva[4], wvb[4];              // cumulative wv slices for g-loop (pass>0)
    float cwv = 0.f;                 // cumulative wv at lane (tmi, d=tc)

    for (int pass = 0; pass < 3; ++pass) {
        vf2 xa[4], xb[4];
        float S[4];
        #pragma unroll
        for (int m = 0; m < 4; ++m) {
            xa[m].x = 0.f; xa[m].y = 0.f;
            xb[m].x = 0.f; xb[m].y = 0.f;
            S[m] = 0.f;
        }

        #pragma unroll 2
        for (int g = 0; g < 8; ++g) {
            const float4 f = inb4[g << 6];
            vf2 fa, fb;
            fa.x = f.x; fa.y = f.y; fb.x = f.z; fb.y = f.w;
            if (pass) {
                #pragma unroll
                for (int m = 0; m < 4; ++m) {
                    vf2 t = fa * wva[m] + fb * wvb[m];   // pk_mul + pk_fma
                    float d = t.x + t.y;
                    d = DPP_ADDF(d, 0xB1);               // quad-sum
                    d = DPP_ADDF(d, 0x4E);
                    const float e = __expf(d);           // quad-uniform
                    S[m] += e;
                    xa[m] += fa * e;
                    xb[m] += fb * e;
                }
            } else {                                     // e = 1, m-independent
                xa[0] += fa; xb[0] += fb;
            }
        }
        if (!pass) {
            #pragma unroll
            for (int m = 1; m < 4; ++m) { xa[m] = xa[0]; xb[m] = xb[0]; }
        }

        // harvest over the 16 lanes sharing c4: row_shl:4/8 put 4-group sums
        // in lanes 0..3; xor16/32 (symmetric) finish. Lanes 0..3 (l==c4) hold
        // xc[m][4*c4+j]; S in vals[16..19].
        float vals[20] = { xa[0].x, xa[0].y, xb[0].x, xb[0].y,
                           xa[1].x, xa[1].y, xb[1].x, xb[1].y,
                           xa[2].x, xa[2].y, xb[2].x, xb[2].y,
                           xa[3].x, xa[3].y, xb[3].x, xb[3].y,
                           S[0], S[1], S[2], S[3] };
        #pragma unroll
        for (int v = 0; v < 20; ++v) {
            float x = vals[v];
            x = DPP_ADDF(x, 0x104);   // lane i += lane i+4
            x = DPP_ADDF(x, 0x108);   // lane i += lane i+8
            x += __shfl_xor(x, 16);
            x += __shfl_xor(x, 32);
            vals[v] = x;
        }
        if (l < 4) {                  // l == c4
            float* rp = &red[w * 68];
            #pragma unroll
            for (int m = 0; m < 4; ++m) {
                #pragma unroll
                for (int j = 0; j < 4; ++j)
                    rp[m * 17 + 1 + (c4 << 2) + j] = vals[(m << 2) + j];
            }
            if (l == 0) {
                #pragma unroll
                for (int m = 0; m < 4; ++m)
                    rp[m * 17] = pass ? vals[16 + m] : 128.f;  // 128 rows/wave
            }
        }
        __syncthreads();              // barrier 1: red complete (+W staged)

        // ---- redundant tail in EVERY wave: lane = (tmi, tc) ----
        float Stot = 0.f, xtot = 0.f;
        #pragma unroll
        for (int w2 = 0; w2 < 16; ++w2) {
            const float* rp = &red[w2 * 68 + tmi * 17];
            Stot += rp[0];
            xtot += rp[1 + tc];       // xc_total[tmi][d=tc]
        }
        // s(tmi,tc) = (1/S) * Sum_d xtot(tmi,d) * W[d][tmi*16+tc]
        float s = 0.f;
        #pragma unroll
        for (int d = 0; d < 16; ++d)
            s += __shfl(xtot, (tmi << 4) + d) * w_lds[d * 65 + (tmi << 4) + tc];
        s /= Stot;
        // squash over the 16-lane group (masks 1,2,4,8 stay in-group)
        float n2 = s * s;
        n2 += __shfl_xor(n2, 1);
        n2 += __shfl_xor(n2, 2);
        n2 += __shfl_xor(n2, 4);
        n2 += __shfl_xor(n2, 8);
        const float nr = sqrtf(n2);
        const float v  = s * (n2 / (1.f + n2)) / (nr + 1e-7f);

        if (pass < 2) {
            // wv(tmi, d=tc) = Sum_c2 W[d=tc][tmi*16+c2] * v(tmi,c2)
            float wvv = 0.f;
            #pragma unroll
            for (int c2 = 0; c2 < 16; ++c2)
                wvv += w_lds[tc * 65 + (tmi << 4) + c2] * __shfl(v, (tmi << 4) + c2);
            cwv = (pass == 0) ? wvv : (cwv + wvv);
            // redistribute cum-wv to g-loop layout: lane needs wv[m][4*c4+j]
            #pragma unroll
            for (int m = 0; m < 4; ++m) {
                wva[m].x = __shfl(cwv, (m << 4) + (c4 << 2) + 0);
                wva[m].y = __shfl(cwv, (m << 4) + (c4 << 2) + 1);
                wvb[m].x = __shfl(cwv, (m << 4) + (c4 << 2) + 2);
                wvb[m].y = __shfl(cwv, (m << 4) + (c4 << 2) + 3);
            }
            __syncthreads();          // barrier 2: red consumed; next pass may rewrite
        } else {
            if (w == 0)
                out[((size_t)b << 9) + ((m0 + tmi) << 4) + tc] = v;
        }
    }
}

extern "C" void kernel_launch(void* const* d_in, const int* in_sizes, int n_in,
                              void* d_out, int out_size, void* d_ws, size_t ws_size,
                              hipStream_t stream) {
    (void)in_sizes; (void)n_in; (void)d_ws; (void)ws_size; (void)out_size;
    const float* in = (const float*)d_in[0];
    const float* W  = (const float*)d_in[1];
    float* out = (float*)d_out;
    hipLaunchKernelGGL(capsule_routing_kernel, dim3(512), dim3(TPB), 0, stream,
                       in, W, out);
}

// Round 10
// 79.197 us; speedup vs baseline: 1.2525x; 1.2525x over previous
//
#include <hip/hip_runtime.h>
#include <math.h>

// CapsuleLayer dynamic routing, factored (u_hat never materialized):
//   s[b,m,:] = ((Sum_n e_n in[b,n,:]) / Sum_n e_n) @ W[:,m,:],  e_n = exp(logit)
//   logit linear in per-pass wv updates -> cumulative wv, no per-n state.
//   Pass 0 (uniform softmax) = plain column sum, S = 2048.
//
// Cross-round evidence: __shfl == ds_bpermute (DS pipe!). DS-light rounds
// (R7/R8 ~33-35us) beat DS-heavy ones (R5 52, R9 50 + 786K bank conflicts).
// R10 = R8 structure with DS stripped:
//  (1) Harvest: DPP row_shl:4/8 (VALU) only — NO xor16/32 shfl. Lanes 0..3 of
//      each row-of-16 write 4 sub-partials/wave to red[32][69] (stride 69 ->
//      store bank pattern 5*rg+4*c4 all-distinct, conflict-free).
//  (2) Single tail wave sums all 32 partials directly (fin stage deleted);
//      2 barriers/pass (red-ready, cum-ready), 5 total.
//  (3) Pass-0 harvest is 4 values (column sum m-independent, S const).
// Kept: dense loads (lane=(row,c4): 1 instr = 64 distinct 64B lines), quad
// dot via DPP quad_perm 0xB1/0x4E, pk_fma float2 math, W in LDS stride 65,
// b = bx&63 pins batch to XCD b%8, launch_bounds(512,2) = 128-VGPR budget
// (compiler rule VGPR=256/min_waves, measured R1-R5; grid caps at 2 blk/CU
// anyway so the budget costs nothing).

#define TPB 512

typedef float vf2 __attribute__((ext_vector_type(2)));

// x + dpp_shuffled(x); bound_ctrl=true -> out-of-pattern lanes contribute 0
#define DPP_ADDF(x, ctrl) \
    ((x) + __int_as_float(__builtin_amdgcn_update_dpp( \
        0, __float_as_int(x), (ctrl), 0xF, 0xF, true)))
// quad_perm xor1 = 0xB1, xor2 = 0x4E; row_shl:4 = 0x104, row_shl:8 = 0x108

__global__ __launch_bounds__(TPB, 2)
void capsule_routing_kernel(const float* __restrict__ in,
                            const float* __restrict__ W,
                            float* __restrict__ out)
{
    __shared__ float red[32 * 69];   // [wave*4+rowof16][m*17 + {S, xc[16]}]
    __shared__ float cum[64];        // cumulative wv[tmi][d]
    __shared__ float w_lds[16 * 65]; // W[d][tmi*16+c], stride 65

    const int tid = threadIdx.x;
    const int w   = tid >> 6;        // 0..7
    const int l   = tid & 63;
    const int c4  = l & 3;           // dim-quarter of row
    const int rg  = l >> 4;          // row-of-16 within wave (0..3)
    const int b   = blockIdx.x & 63;
    const int m0  = (blockIdx.x >> 6) << 2;

    // dense: lane l reads float4 #(w*1024 + g*64 + l); wave w owns rows
    // [w*256, w*256+256), g = 0..15
    const float4* __restrict__ inb4 =
        (const float4*)(in + ((size_t)b << 15)) + ((w << 10) + l);

    // stage W[:, m0:m0+4, :] (1024 floats) -> LDS, stride-65 rows.
    // Ordered before first use by pass-0's red barrier.
    #pragma unroll
    for (int k = 0; k < 2; ++k) {
        const int idx = tid + k * TPB;
        const int d = idx >> 6, r = idx & 63;
        w_lds[d * 65 + r] = W[(d << 9) + (m0 << 4) + r];
    }

    float cwv = 0.f;                 // tail-wave cumulative wv (lane = tmi,tc)

    for (int pass = 0; pass < 3; ++pass) {
        vf2 wva[4], wvb[4];
        if (pass) {
            const float4* cp = (const float4*)cum;   // 16-way broadcast reads
            #pragma unroll
            for (int m = 0; m < 4; ++m) {
                const float4 q = cp[(m << 2) + c4];  // cum[m*16 + c4*4 ..+3]
                wva[m].x = q.x; wva[m].y = q.y;
                wvb[m].x = q.z; wvb[m].y = q.w;
            }
        }

        vf2 xa[4], xb[4];
        float S[4];
        #pragma unroll
        for (int m = 0; m < 4; ++m) {
            xa[m].x = 0.f; xa[m].y = 0.f;
            xb[m].x = 0.f; xb[m].y = 0.f;
            S[m] = 0.f;
        }

        #pragma unroll 2
        for (int g = 0; g < 16; ++g) {
            const float4 f = inb4[g << 6];
            vf2 fa, fb;
            fa.x = f.x; fa.y = f.y; fb.x = f.z; fb.y = f.w;
            if (pass) {
                #pragma unroll
                for (int m = 0; m < 4; ++m) {
                    vf2 t = fa * wva[m] + fb * wvb[m];   // pk_mul + pk_fma
                    float d = t.x + t.y;
                    d = DPP_ADDF(d, 0xB1);               // quad-sum (VALU)
                    d = DPP_ADDF(d, 0x4E);
                    const float e = __expf(d);           // quad-uniform
                    S[m] += e;
                    xa[m] += fa * e;
                    xb[m] += fb * e;
                }
            } else {                                     // e = 1, m-independent
                xa[0] += fa; xb[0] += fb;
            }
        }

        // harvest: row_shl:4 + row_shl:8 (VALU DPP) -> lanes 0..3 of each
        // row-of-16 hold that row-of-16's c4-group sums. 16 active lanes
        // write sub-partials; NO cross-row shuffle (tail merges 32 partials).
        const int pbase = ((w << 2) + rg) * 69;
        if (pass) {
            float vals[20] = { xa[0].x, xa[0].y, xb[0].x, xb[0].y,
                               xa[1].x, xa[1].y, xb[1].x, xb[1].y,
                               xa[2].x, xa[2].y, xb[2].x, xb[2].y,
                               xa[3].x, xa[3].y, xb[3].x, xb[3].y,
                               S[0], S[1], S[2], S[3] };
            #pragma unroll
            for (int v = 0; v < 20; ++v) {
                float x = vals[v];
                x = DPP_ADDF(x, 0x104);   // lane i += lane i+4
                x = DPP_ADDF(x, 0x108);   // lane i += lane i+8
                vals[v] = x;
            }
            if ((l & 15) < 4) {           // l&15 == c4
                #pragma unroll
                for (int m = 0; m < 4; ++m) {
                    #pragma unroll
                    for (int j = 0; j < 4; ++j)
                        red[pbase + m * 17 + 1 + (c4 << 2) + j] = vals[(m << 2) + j];
                }
                if ((l & 15) == 0) {
                    #pragma unroll
                    for (int m = 0; m < 4; ++m)
                        red[pbase + m * 17] = vals[16 + m];
                }
            }
        } else {
            float vals[4] = { xa[0].x, xa[0].y, xb[0].x, xb[0].y };
            #pragma unroll
            for (int v = 0; v < 4; ++v) {
                float x = vals[v];
                x = DPP_ADDF(x, 0x104);
                x = DPP_ADDF(x, 0x108);
                vals[v] = x;
            }
            if ((l & 15) < 4) {
                #pragma unroll
                for (int j = 0; j < 4; ++j)
                    red[pbase + 1 + (c4 << 2) + j] = vals[j];
            }
        }
        __syncthreads();                  // red ready (also orders W staging)

        // ---- tail: wave 0 only. lane = (tmi = l>>4, tc = l&15) ----
        if (w == 0) {
            const int tmi = rg;           // l>>4
            const int tc  = l & 15;
            float Stot = 0.f, xtot = 0.f;
            if (pass) {
                #pragma unroll
                for (int p = 0; p < 32; ++p) {
                    Stot += red[p * 69 + tmi * 17];
                    xtot += red[p * 69 + tmi * 17 + 1 + tc];
                }
            } else {
                Stot = 2048.f;
                #pragma unroll
                for (int p = 0; p < 32; ++p)
                    xtot += red[p * 69 + 1 + tc];   // m0 slots; same for all m
            }
            // s(tmi,tc) = (1/S) Sum_d xtot(tmi,d) * W[d][tmi*16+tc]
            float s = 0.f;
            #pragma unroll
            for (int d = 0; d < 16; ++d)
                s += __shfl(xtot, (tmi << 4) + d) * w_lds[d * 65 + (tmi << 4) + tc];
            s /= Stot;
            float n2 = s * s;
            n2 += __shfl_xor(n2, 1);
            n2 += __shfl_xor(n2, 2);
            n2 += __shfl_xor(n2, 4);
            n2 += __shfl_xor(n2, 8);
            const float nr = sqrtf(n2);
            const float v  = s * (n2 / (1.f + n2)) / (nr + 1e-7f);
            if (pass < 2) {
                float wvv = 0.f;          // wv(tmi, d=tc)
                #pragma unroll
                for (int c2 = 0; c2 < 16; ++c2)
                    wvv += w_lds[tc * 65 + (tmi << 4) + c2] * __shfl(v, (tmi << 4) + c2);
                cwv += wvv;               // cwv starts at 0; accumulates per pass
                cum[(tmi << 4) + tc] = cwv;
            } else {
                out[((size_t)b << 9) + ((m0 + tmi) << 4) + tc] = v;
            }
        }
        if (pass < 2) __syncthreads();    // cum ready; red free for next pass
    }
}

extern "C" void kernel_launch(void* const* d_in, const int* in_sizes, int n_in,
                              void* d_out, int out_size, void* d_ws, size_t ws_size,
                              hipStream_t stream) {
    (void)in_sizes; (void)n_in; (void)d_ws; (void)ws_size; (void)out_size;
    const float* in = (const float*)d_in[0];
    const float* W  = (const float*)d_in[1];
    float* out = (float*)d_out;
    hipLaunchKernelGGL(capsule_routing_kernel, dim3(512), dim3(TPB), 0, stream,
                       in, W, out);
}